// Round 2
// baseline (1506.730 us; speedup 1.0000x reference)
//
#include <hip/hip_runtime.h>
#include <hip/hip_bf16.h>

typedef __hip_bfloat16 bf16;

__device__ __forceinline__ float b2f(bf16 v){ return __bfloat162float(v); }
__device__ __forceinline__ bf16 f2b(float f){ return __float2bfloat16(f); }
__device__ __forceinline__ float gelu_exact(float x){
    return 0.5f * x * (1.0f + erff(x * 0.70710678118654752440f));
}

#define HW 16384          // 128*128
#define NPLANE 1048576    // 64*16384 per batch
#define EPS 1e-5f

// ---------------- Kernel 1: per-(b,c) LN stats over H*W ----------------
__global__ __launch_bounds__(256) void k_stats(const float* __restrict__ x,
                                               float* __restrict__ mu,
                                               float* __restrict__ rinv){
    int bc = blockIdx.x;                       // 0..1023
    const float* p = x + (size_t)bc * HW;
    float s = 0.f, ss = 0.f;
    for (int i = threadIdx.x; i < HW; i += 256){
        float v = p[i]; s += v; ss += v*v;
    }
    __shared__ float rs[256], rss[256];
    rs[threadIdx.x] = s; rss[threadIdx.x] = ss; __syncthreads();
    for (int st = 128; st > 0; st >>= 1){
        if (threadIdx.x < st){ rs[threadIdx.x] += rs[threadIdx.x+st]; rss[threadIdx.x] += rss[threadIdx.x+st]; }
        __syncthreads();
    }
    if (threadIdx.x == 0){
        float m = rs[0] * (1.f/HW);
        float v = rss[0] * (1.f/HW) - m*m;
        mu[bc] = m; rinv[bc] = rsqrtf(v + EPS);
    }
}

// ---------------- Kernel 2: LN1 + 1x1 conv, both branches ----------------
// y_br[b,o,hw] = g1[hw]*sum_c(W[o,c]*xn[b,c,hw]) + b1[hw]*rowsum(W)[o] + cb[o]
__global__ __launch_bounds__(256) void k_conv(const float* __restrict__ x,
                                              const float* __restrict__ mu,
                                              const float* __restrict__ rinv,
                                              const float* __restrict__ g1a, const float* __restrict__ b1a,
                                              const float* __restrict__ w1,  const float* __restrict__ cb1,
                                              const float* __restrict__ g1b, const float* __restrict__ b1b,
                                              const float* __restrict__ w2,  const float* __restrict__ cb2,
                                              float* __restrict__ y1, float* __restrict__ y2){
    int blk = blockIdx.x;          // 16 * 256
    int b = blk >> 8; int tile = blk & 255; int hw0 = tile * 64;
    __shared__ float a[64][65];
    __shared__ float w[64][64];
    __shared__ float rowsum[64];
    int tid = threadIdx.x;

    for (int e = tid; e < 4096; e += 256){
        int c = e >> 6, p = e & 63;
        int bc = b*64 + c;
        float v = x[(size_t)bc * HW + hw0 + p];
        a[c][p] = (v - mu[bc]) * rinv[bc];
    }
    for (int br = 0; br < 2; br++){
        const float* W  = br ? w2  : w1;
        const float* cb = br ? cb2 : cb1;
        const float* gp = br ? g1b : g1a;
        const float* bp = br ? b1b : b1a;
        float* y = br ? y2 : y1;
        __syncthreads();                       // a ready / previous w usage done
        for (int e = tid; e < 4096; e += 256) w[e>>6][e&63] = W[e];
        __syncthreads();
        if (tid < 64){ float s = 0.f; for (int c = 0; c < 64; c++) s += w[tid][c]; rowsum[tid] = s; }
        __syncthreads();
        int p = tid & 63, oq = tid >> 6;
        int hw = hw0 + p;
        float gl = gp[hw], bl = bp[hw];
        for (int o = oq*16; o < oq*16 + 16; o++){
            float acc = 0.f;
            #pragma unroll
            for (int c = 0; c < 64; c++) acc += w[o][c] * a[c][p];
            float val = gl * acc + bl * rowsum[o] + cb[o];
            y[(size_t)(b*64 + o) * HW + hw] = val;
        }
    }
}

// ---------------- Kernel 3: LN2 over (H,W) + exact GELU, in place ----------------
__global__ __launch_bounds__(256) void k_ln2gelu(float* __restrict__ y1, float* __restrict__ y2,
                                                 const float* __restrict__ g2a, const float* __restrict__ b2a,
                                                 const float* __restrict__ g2b, const float* __restrict__ b2b){
    int blk = blockIdx.x;                      // 2048: br*1024 + bc
    int br = blk >> 10; int bc = blk & 1023;
    float* y = br ? y2 : y1;
    const float* g  = br ? g2b : g2a;
    const float* bb = br ? b2b : b2a;
    float* p = y + (size_t)bc * HW;
    float s = 0.f, ss = 0.f;
    for (int i = threadIdx.x; i < HW; i += 256){
        float v = p[i]; s += v; ss += v*v;
    }
    __shared__ float rs[256], rss[256];
    __shared__ float smu, srinv;
    rs[threadIdx.x] = s; rss[threadIdx.x] = ss; __syncthreads();
    for (int st = 128; st > 0; st >>= 1){
        if (threadIdx.x < st){ rs[threadIdx.x] += rs[threadIdx.x+st]; rss[threadIdx.x] += rss[threadIdx.x+st]; }
        __syncthreads();
    }
    if (threadIdx.x == 0){
        float m = rs[0] * (1.f/HW);
        float v = rss[0] * (1.f/HW) - m*m;
        smu = m; srinv = rsqrtf(v + EPS);
    }
    __syncthreads();
    for (int i = threadIdx.x; i < HW; i += 256){
        float v = (p[i] - smu) * srinv * g[i] + bb[i];
        p[i] = gelu_exact(v);
    }
}

// ---------------- Kernel 4: per-window attention + LAM + proj ----------------
// x1 lives in d_out; xo is written in place over x1 (per-block address set,
// all x1 reads precede the final store within the block).
__global__ __launch_bounds__(256) void k_attn(float* __restrict__ x1, const float* __restrict__ x2,
                                              const float* __restrict__ pos1, const float* __restrict__ pos2,
                                              const float* __restrict__ qw, const float* __restrict__ qb,
                                              const float* __restrict__ kvw, const float* __restrict__ kvb,
                                              const float* __restrict__ rpb, const float* __restrict__ gammap,
                                              const float* __restrict__ pw, const float* __restrict__ pb){
    int wid = blockIdx.x;                      // 4096 windows
    int b = wid >> 8; int r = wid & 255; int hy = r >> 4; int wx = r & 15;

    __shared__ float qs[64][65];               // scaled q  (t, c)
    __shared__ float ks[64][65];               // k (t, c); later Y (t, c); later proj out
    __shared__ float buf[64][65];              // x2w -> x1w -> per-head probs -> xo
    __shared__ bf16  vs[64][68];               // v (t, c) bf16; o overwrites per-head cols
    __shared__ float soft[16][16];
    __shared__ float energy[16][16];

    int tid = threadIdx.x; int lane = tid & 63; int wq = tid >> 6;
    size_t base = (size_t)b * NPLANE;
    #define HWOF(t) ((hy*8 + ((t)>>3))*128 + wx*8 + ((t)&7))

    // ---- load x2w ----
    for (int e = tid; e < 4096; e += 256){
        int t = e & 63, c = e >> 6;
        buf[t][c] = x2[base + (size_t)c*HW + HWOF(t)] + pos2[t*64 + c];
    }
    __syncthreads();
    // ---- k, v ----
    {
        int co = lane;
        float wr[64];
        #pragma unroll
        for (int c = 0; c < 64; c++) wr[c] = kvw[co*64 + c];
        float bk = kvb[co];
        for (int t = wq; t < 64; t += 4){
            float acc = bk;
            #pragma unroll
            for (int c = 0; c < 64; c++) acc += buf[t][c] * wr[c];
            ks[t][co] = acc;
        }
        #pragma unroll
        for (int c = 0; c < 64; c++) wr[c] = kvw[(64+co)*64 + c];
        float bv = kvb[64 + co];
        for (int t = wq; t < 64; t += 4){
            float acc = bv;
            #pragma unroll
            for (int c = 0; c < 64; c++) acc += buf[t][c] * wr[c];
            vs[t][co] = f2b(acc);
        }
    }
    __syncthreads();
    // ---- load x1w ----
    for (int e = tid; e < 4096; e += 256){
        int t = e & 63, c = e >> 6;
        buf[t][c] = x1[base + (size_t)c*HW + HWOF(t)] + pos1[t*64 + c];
    }
    __syncthreads();
    // ---- q (scaled) ----
    {
        int co = lane;
        float wr[64];
        #pragma unroll
        for (int c = 0; c < 64; c++) wr[c] = qw[co*64 + c];
        float bq = qb[co];
        for (int t = wq; t < 64; t += 4){
            float acc = bq;
            #pragma unroll
            for (int c = 0; c < 64; c++) acc += buf[t][c] * wr[c];
            qs[t][co] = acc * 0.25f;
        }
    }
    __syncthreads();

    // ---- per-head: scores -> softmax (wave shuffles) -> o ----
    for (int h = 0; h < 4; h++){
        {
            int u = lane;
            int uy = u >> 3, ux = u & 7;
            float pr[16];
            #pragma unroll
            for (int j = 0; j < 16; j++){
                int t = wq + 4*j;
                int ty = t >> 3, tx = t & 7;
                int idx = (ty - uy + 7)*15 + (tx - ux + 7);
                float acc = rpb[idx*4 + h];
                #pragma unroll
                for (int d = 0; d < 16; d++) acc += qs[t][h*16 + d] * ks[u][h*16 + d];
                pr[j] = acc;
            }
            #pragma unroll
            for (int j = 0; j < 16; j++){
                float m = pr[j];
                for (int off = 32; off; off >>= 1) m = fmaxf(m, __shfl_xor(m, off));
                float e = __expf(pr[j] - m);
                float ssum = e;
                for (int off = 32; off; off >>= 1) ssum += __shfl_xor(ssum, off);
                buf[wq + 4*j][u] = e / ssum;
            }
        }
        __syncthreads();
        float oacc[4];
        {
            int d = tid & 15; int tq = tid >> 4;
            #pragma unroll
            for (int jj = 0; jj < 4; jj++){
                int t = tq + 16*jj;
                float acc = 0.f;
                #pragma unroll
                for (int u = 0; u < 64; u++) acc += buf[t][u] * b2f(vs[u][h*16 + d]);
                oacc[jj] = acc;
            }
        }
        __syncthreads();       // all v reads done before overwrite
        {
            int d = tid & 15; int tq = tid >> 4;
            #pragma unroll
            for (int jj = 0; jj < 4; jj++) vs[tq + 16*jj][h*16 + d] = f2b(oacc[jj]);
        }
        __syncthreads();
    }

    // ---- LAM: energy (16x16, K=256) -> softmax -> Y into ks ----
    {
        int i = tid >> 4; int j = tid & 15;
        float acc = 0.f;
        for (int k = 0; k < 256; k++){
            int t = k & 63, cb0 = (k >> 6) * 16;
            acc += b2f(vs[t][cb0 + i]) * b2f(vs[t][cb0 + j]);
        }
        energy[i][j] = acc;
    }
    __syncthreads();
    if (tid < 16){
        int i = tid; float m = -1e30f;
        for (int j = 0; j < 16; j++) m = fmaxf(m, energy[i][j]);
        float s = 0.f; float ex[16];
        for (int j = 0; j < 16; j++){ ex[j] = __expf(energy[i][j] - m); s += ex[j]; }
        float inv = 1.f / s;
        for (int j = 0; j < 16; j++) soft[i][j] = ex[j] * inv;
    }
    __syncthreads();
    {
        float g = gammap[0];
        int t = lane; int cb0 = 16 * wq;       // k = wq*64 + t, head = wq
        float yv[16];
        #pragma unroll
        for (int j = 0; j < 16; j++) yv[j] = b2f(vs[t][cb0 + j]);
        #pragma unroll
        for (int i = 0; i < 16; i++){
            float acc = 0.f;
            #pragma unroll
            for (int j = 0; j < 16; j++) acc += soft[i][j] * yv[j];
            ks[t][cb0 + i] = g * acc + yv[i];
        }
    }
    __syncthreads();

    // ---- xo = Y + q + x1w into buf (reload x1 from global) ----
    for (int e = tid; e < 4096; e += 256){
        int t = e & 63, c = e >> 6;
        buf[t][c] = ks[t][c] + qs[t][c]
                  + x1[base + (size_t)c*HW + HWOF(t)] + pos1[t*64 + c];
    }
    __syncthreads();
    // ---- proj into ks ----
    {
        int co = lane;
        float wr[64];
        #pragma unroll
        for (int c = 0; c < 64; c++) wr[c] = pw[co*64 + c];
        float bp = pb[co];
        for (int t = wq; t < 64; t += 4){
            float acc = bp;
            #pragma unroll
            for (int c = 0; c < 64; c++) acc += buf[t][c] * wr[c];
            ks[t][co] = acc;
        }
    }
    __syncthreads();
    // ---- store xo in place over x1 ----
    for (int e = tid; e < 4096; e += 256){
        int t = e & 63, c = e >> 6;
        x1[base + (size_t)c*HW + HWOF(t)] = ks[t][c];
    }
    #undef HWOF
}

// ---------------- Kernel 5: channel-MLP with pre-LN, in place on xo ----------------
__global__ __launch_bounds__(256) void k_mlp(float* __restrict__ xo,
                                             const float* __restrict__ g, const float* __restrict__ bb,
                                             const float* __restrict__ w1, const float* __restrict__ b1,
                                             const float* __restrict__ w2, const float* __restrict__ b2){
    __shared__ float W1[64][64], W2[64][64];
    int tid = threadIdx.x;
    for (int e = tid; e < 4096; e += 256){ W1[e>>6][e&63] = w1[e]; W2[e>>6][e&63] = w2[e]; }
    __syncthreads();
    int gp = blockIdx.x * 256 + tid;           // 262144 positions
    int b = gp >> 14, hw = gp & 16383;
    size_t base = (size_t)b * NPLANE + hw;

    float t[64];
    float mean = 0.f;
    #pragma unroll
    for (int c = 0; c < 64; c++){ t[c] = xo[base + (size_t)c*HW]; mean += t[c]; }
    mean *= (1.f/64.f);
    float var = 0.f;
    #pragma unroll
    for (int c = 0; c < 64; c++){ float d = t[c] - mean; var += d*d; }
    var *= (1.f/64.f);
    float rstd = rsqrtf(var + EPS);
    float tn[64];
    #pragma unroll
    for (int c = 0; c < 64; c++) tn[c] = (t[c] - mean) * rstd * g[c] + bb[c];

    float h1[64];
    #pragma unroll
    for (int j = 0; j < 64; j++){
        float acc = b1[j];
        #pragma unroll
        for (int c = 0; c < 64; c++) acc += tn[c] * W1[j][c];
        h1[j] = gelu_exact(acc);
    }
    #pragma unroll
    for (int c2 = 0; c2 < 64; c2++){
        float acc = b2[c2];
        #pragma unroll
        for (int j = 0; j < 64; j++) acc += h1[j] * W2[c2][j];
        xo[base + (size_t)c2*HW] = t[c2] + acc;
    }
}

extern "C" void kernel_launch(void* const* d_in, const int* in_sizes, int n_in,
                              void* d_out, int out_size, void* d_ws, size_t ws_size,
                              hipStream_t stream){
    const float* x        = (const float*)d_in[0];
    const float* l1_g1    = (const float*)d_in[1];
    const float* l1_b1    = (const float*)d_in[2];
    const float* l1_cw    = (const float*)d_in[3];
    const float* l1_cb    = (const float*)d_in[4];
    const float* l1_g2    = (const float*)d_in[5];
    const float* l1_b2    = (const float*)d_in[6];
    const float* l2_g1    = (const float*)d_in[7];
    const float* l2_b1    = (const float*)d_in[8];
    const float* l2_cw    = (const float*)d_in[9];
    const float* l2_cb    = (const float*)d_in[10];
    const float* l2_g2    = (const float*)d_in[11];
    const float* l2_b2    = (const float*)d_in[12];
    const float* pos1     = (const float*)d_in[13];
    const float* pos2     = (const float*)d_in[14];
    const float* q_w      = (const float*)d_in[15];
    const float* q_b      = (const float*)d_in[16];
    const float* kv_w     = (const float*)d_in[17];
    const float* kv_b     = (const float*)d_in[18];
    const float* rpb      = (const float*)d_in[19];
    const float* gamma    = (const float*)d_in[20];
    const float* proj_w   = (const float*)d_in[21];
    const float* proj_b   = (const float*)d_in[22];
    const float* norm2_g  = (const float*)d_in[23];
    const float* norm2_b  = (const float*)d_in[24];
    const float* fc1_w    = (const float*)d_in[25];
    const float* fc1_b    = (const float*)d_in[26];
    const float* fc2_w    = (const float*)d_in[27];
    const float* fc2_b    = (const float*)d_in[28];

    float* out = (float*)d_out;                // y1 -> xo -> final, in place

    float* y2   = (float*)d_ws;                // 16.7M floats (67 MB)
    float* mu   = y2 + (size_t)16*NPLANE;
    float* rinv = mu + 1024;

    k_stats  <<<1024, 256, 0, stream>>>(x, mu, rinv);
    k_conv   <<<4096, 256, 0, stream>>>(x, mu, rinv,
                                        l1_g1, l1_b1, l1_cw, l1_cb,
                                        l2_g1, l2_b1, l2_cw, l2_cb, out, y2);
    k_ln2gelu<<<2048, 256, 0, stream>>>(out, y2, l1_g2, l1_b2, l2_g2, l2_b2);
    k_attn   <<<4096, 256, 0, stream>>>(out, y2, pos1, pos2, q_w, q_b, kv_w, kv_b,
                                        rpb, gamma, proj_w, proj_b);
    k_mlp    <<<1024, 256, 0, stream>>>(out, norm2_g, norm2_b, fc1_w, fc1_b, fc2_w, fc2_b);
}

// Round 3
// 849.752 us; speedup vs baseline: 1.7731x; 1.7731x over previous
//
#include <hip/hip_runtime.h>
#include <hip/hip_bf16.h>

typedef __hip_bfloat16 bf16;
typedef __attribute__((ext_vector_type(8))) short short8;
typedef __attribute__((ext_vector_type(4))) short short4v;
typedef __attribute__((ext_vector_type(4))) float float4v;

__device__ __forceinline__ float b2f(bf16 v){ return __bfloat162float(v); }
__device__ __forceinline__ bf16 f2b(float f){ return __float2bfloat16(f); }
__device__ __forceinline__ short f2bs(float f){
    union { bf16 h; short s; } u; u.h = __float2bfloat16(f); return u.s;
}
__device__ __forceinline__ float bs2f(short s){
    return __uint_as_float(((unsigned)(unsigned short)s) << 16);
}
__device__ __forceinline__ float gelu_exact(float x){
    return 0.5f * x * (1.0f + erff(x * 0.70710678118654752440f));
}
// load 8 consecutive floats -> bf16 frag
__device__ __forceinline__ short8 load_w8(const float* p){
    float4v w0 = *(const float4v*)p;
    float4v w1 = *(const float4v*)(p + 4);
    short8 r;
    r[0]=f2bs(w0[0]); r[1]=f2bs(w0[1]); r[2]=f2bs(w0[2]); r[3]=f2bs(w0[3]);
    r[4]=f2bs(w1[0]); r[5]=f2bs(w1[1]); r[6]=f2bs(w1[2]); r[7]=f2bs(w1[3]);
    return r;
}
#define MFMA(a,b,c) __builtin_amdgcn_mfma_f32_16x16x32_bf16((a),(b),(c),0,0,0)

#define HW 16384          // 128*128
#define NPLANE 1048576    // 64*16384 per batch
#define EPS 1e-5f
#define LS 72             // LDS row stride in bf16 (144 B, 16B-aligned rows)

// ---------------- Kernel 1: per-(b,c) LN stats over H*W ----------------
__global__ __launch_bounds__(256) void k_stats(const float* __restrict__ x,
                                               float* __restrict__ mu,
                                               float* __restrict__ rinv){
    int bc = blockIdx.x;                       // 0..1023
    const float* p = x + (size_t)bc * HW;
    float s = 0.f, ss = 0.f;
    for (int i = threadIdx.x; i < HW; i += 256){
        float v = p[i]; s += v; ss += v*v;
    }
    __shared__ float rs[256], rss[256];
    rs[threadIdx.x] = s; rss[threadIdx.x] = ss; __syncthreads();
    for (int st = 128; st > 0; st >>= 1){
        if (threadIdx.x < st){ rs[threadIdx.x] += rs[threadIdx.x+st]; rss[threadIdx.x] += rss[threadIdx.x+st]; }
        __syncthreads();
    }
    if (threadIdx.x == 0){
        float m = rs[0] * (1.f/HW);
        float v = rss[0] * (1.f/HW) - m*m;
        mu[bc] = m; rinv[bc] = rsqrtf(v + EPS);
    }
}

// ---------------- Kernel 2: LN1 + 1x1 conv, both branches ----------------
__global__ __launch_bounds__(256) void k_conv(const float* __restrict__ x,
                                              const float* __restrict__ mu,
                                              const float* __restrict__ rinv,
                                              const float* __restrict__ g1a, const float* __restrict__ b1a,
                                              const float* __restrict__ w1,  const float* __restrict__ cb1,
                                              const float* __restrict__ g1b, const float* __restrict__ b1b,
                                              const float* __restrict__ w2,  const float* __restrict__ cb2,
                                              float* __restrict__ y1, float* __restrict__ y2){
    int blk = blockIdx.x;          // 16 * 256
    int b = blk >> 8; int tile = blk & 255; int hw0 = tile * 64;
    __shared__ float a[64][65];
    __shared__ float w[64][64];
    __shared__ float rowsum[64];
    int tid = threadIdx.x;

    for (int e = tid; e < 4096; e += 256){
        int c = e >> 6, p = e & 63;
        int bc = b*64 + c;
        float v = x[(size_t)bc * HW + hw0 + p];
        a[c][p] = (v - mu[bc]) * rinv[bc];
    }
    for (int br = 0; br < 2; br++){
        const float* W  = br ? w2  : w1;
        const float* cb = br ? cb2 : cb1;
        const float* gp = br ? g1b : g1a;
        const float* bp = br ? b1b : b1a;
        float* y = br ? y2 : y1;
        __syncthreads();
        for (int e = tid; e < 4096; e += 256) w[e>>6][e&63] = W[e];
        __syncthreads();
        if (tid < 64){ float s = 0.f; for (int c = 0; c < 64; c++) s += w[tid][c]; rowsum[tid] = s; }
        __syncthreads();
        int p = tid & 63, oq = tid >> 6;
        int hw = hw0 + p;
        float gl = gp[hw], bl = bp[hw];
        for (int o = oq*16; o < oq*16 + 16; o++){
            float acc = 0.f;
            #pragma unroll
            for (int c = 0; c < 64; c++) acc += w[o][c] * a[c][p];
            float val = gl * acc + bl * rowsum[o] + cb[o];
            y[(size_t)(b*64 + o) * HW + hw] = val;
        }
    }
}

// ---------------- Kernel 3: LN2 over (H,W) + exact GELU, in place ----------------
__global__ __launch_bounds__(256) void k_ln2gelu(float* __restrict__ y1, float* __restrict__ y2,
                                                 const float* __restrict__ g2a, const float* __restrict__ b2a,
                                                 const float* __restrict__ g2b, const float* __restrict__ b2b){
    int blk = blockIdx.x;                      // 2048: br*1024 + bc
    int br = blk >> 10; int bc = blk & 1023;
    float* y = br ? y2 : y1;
    const float* g  = br ? g2b : g2a;
    const float* bb = br ? b2b : b2a;
    float* p = y + (size_t)bc * HW;
    float s = 0.f, ss = 0.f;
    for (int i = threadIdx.x; i < HW; i += 256){
        float v = p[i]; s += v; ss += v*v;
    }
    __shared__ float rs[256], rss[256];
    __shared__ float smu, srinv;
    rs[threadIdx.x] = s; rss[threadIdx.x] = ss; __syncthreads();
    for (int st = 128; st > 0; st >>= 1){
        if (threadIdx.x < st){ rs[threadIdx.x] += rs[threadIdx.x+st]; rss[threadIdx.x] += rss[threadIdx.x+st]; }
        __syncthreads();
    }
    if (threadIdx.x == 0){
        float m = rs[0] * (1.f/HW);
        float v = rss[0] * (1.f/HW) - m*m;
        smu = m; srinv = rsqrtf(v + EPS);
    }
    __syncthreads();
    for (int i = threadIdx.x; i < HW; i += 256){
        float v = (p[i] - smu) * srinv * g[i] + bb[i];
        p[i] = gelu_exact(v);
    }
}

// ---------------- Kernel 4: per-window attention + LAM + proj (MFMA) ----------------
// x1 lives in d_out; xo written in place over x1 (same per-block address set).
__global__ __launch_bounds__(256) void k_attn(float* __restrict__ x1, const float* __restrict__ x2,
                                              const float* __restrict__ pos1, const float* __restrict__ pos2,
                                              const float* __restrict__ qw, const float* __restrict__ qb,
                                              const float* __restrict__ kvw, const float* __restrict__ kvb,
                                              const float* __restrict__ rpb, const float* __restrict__ gammap,
                                              const float* __restrict__ pw, const float* __restrict__ pb){
    int wid = blockIdx.x;                      // 4096 windows
    int b = wid >> 8; int r0 = wid & 255; int hy = r0 >> 4; int wx = r0 & 15;

    __shared__ __align__(16) short bufA[64*LS];   // X2 -> X1 (bf16, +pos)
    __shared__ __align__(16) short bufK[64*LS];   // K[t][c] -> O2[t][c] (per-head cols recycled)
    __shared__ __align__(16) short bufV[64*LS];   // VT[c][t] -> OT[c][t] (per-head rows recycled)
    __shared__ __align__(16) short bufQ[64*LS];   // Q[t][c] (scaled)
    __shared__ __align__(16) short bufP[64*LS];   // P[t][u] per head -> XO[t][c]
    __shared__ float rpb_lds[900];
    __shared__ float energyS[256];
    __shared__ __align__(16) short soft_bf[16*32]; // soft rows, upper 16 cols = 0

    const int tid = threadIdx.x;
    const int wq = tid >> 6, lane = tid & 63, qd = lane >> 4, col = lane & 15;
    size_t base = (size_t)b * NPLANE;
    #define HWOF(t) ((hy*8 + ((t)>>3))*128 + wx*8 + ((t)&7))

    const float4v zf = {0.f,0.f,0.f,0.f};
    const short8 zero8 = {0,0,0,0,0,0,0,0};

    // stage rpb
    for (int i = tid; i < 900; i += 256) rpb_lds[i] = rpb[i];

    // ---- load X2 (+pos2) -> bufA ----
    for (int i = tid; i < 1024; i += 256){
        int c = i >> 4, t0 = (i & 15) * 4;
        float4v v = *(const float4v*)(x2 + base + (size_t)c*HW + HWOF(t0));
        #pragma unroll
        for (int k = 0; k < 4; k++)
            bufA[(t0+k)*LS + c] = f2bs(v[k] + pos2[(t0+k)*64 + c]);
    }
    __syncthreads();

    // ---- VT = Wv · X2^T  (D[m=co][n=u]) ----
    {
        float bvr[4];
        #pragma unroll
        for (int r = 0; r < 4; r++) bvr[r] = kvb[64 + 16*wq + 4*qd + r];
        short8 a0 = load_w8(kvw + (size_t)(64 + 16*wq + col)*64 + 8*qd);
        short8 a1 = load_w8(kvw + (size_t)(64 + 16*wq + col)*64 + 32 + 8*qd);
        #pragma unroll
        for (int jn = 0; jn < 4; jn++){
            int u = 16*jn + col;
            short8 b0 = *(const short8*)&bufA[u*LS + 8*qd];
            short8 b1 = *(const short8*)&bufA[u*LS + 32 + 8*qd];
            float4v acc = zf;
            acc = MFMA(a0, b0, acc);
            acc = MFMA(a1, b1, acc);
            #pragma unroll
            for (int r = 0; r < 4; r++)
                bufV[(16*wq + 4*qd + r)*LS + u] = f2bs(acc[r] + bvr[r]);
        }
    }
    // ---- K = X2 · Wk^T  (D[m=u][n=co]) ----
    {
        short8 ax0 = *(const short8*)&bufA[(16*wq + col)*LS + 8*qd];
        short8 ax1 = *(const short8*)&bufA[(16*wq + col)*LS + 32 + 8*qd];
        #pragma unroll
        for (int jn = 0; jn < 4; jn++){
            int co = 16*jn + col;
            short8 b0 = load_w8(kvw + (size_t)co*64 + 8*qd);
            short8 b1 = load_w8(kvw + (size_t)co*64 + 32 + 8*qd);
            float4v acc = zf;
            acc = MFMA(ax0, b0, acc);
            acc = MFMA(ax1, b1, acc);
            float kb = kvb[co];
            #pragma unroll
            for (int r = 0; r < 4; r++)
                bufK[(16*wq + 4*qd + r)*LS + co] = f2bs(acc[r] + kb);
        }
    }
    __syncthreads();

    // ---- load X1 (+pos1) -> bufA ----
    for (int i = tid; i < 1024; i += 256){
        int c = i >> 4, t0 = (i & 15) * 4;
        float4v v = *(const float4v*)(x1 + base + (size_t)c*HW + HWOF(t0));
        #pragma unroll
        for (int k = 0; k < 4; k++)
            bufA[(t0+k)*LS + c] = f2bs(v[k] + pos1[(t0+k)*64 + c]);
    }
    __syncthreads();

    // ---- Q = 0.25 * (X1 · Wq^T + qb)  (D[m=t][n=co]) ----
    {
        short8 ax0 = *(const short8*)&bufA[(16*wq + col)*LS + 8*qd];
        short8 ax1 = *(const short8*)&bufA[(16*wq + col)*LS + 32 + 8*qd];
        #pragma unroll
        for (int jn = 0; jn < 4; jn++){
            int co = 16*jn + col;
            short8 b0 = load_w8(qw + (size_t)co*64 + 8*qd);
            short8 b1 = load_w8(qw + (size_t)co*64 + 32 + 8*qd);
            float4v acc = zf;
            acc = MFMA(ax0, b0, acc);
            acc = MFMA(ax1, b1, acc);
            float qbv = qb[co];
            #pragma unroll
            for (int r = 0; r < 4; r++)
                bufQ[(16*wq + 4*qd + r)*LS + co] = f2bs((acc[r] + qbv) * 0.25f);
        }
    }
    __syncthreads();

    // rel-pos index table (h-independent)
    int idx_t[4][4];
    #pragma unroll
    for (int jn = 0; jn < 4; jn++){
        int u = 16*jn + col; int uy = u >> 3, ux = u & 7;
        #pragma unroll
        for (int r = 0; r < 4; r++){
            int t = 16*wq + 4*qd + r;
            idx_t[jn][r] = ((t>>3) - uy + 7)*15 + ((t&7) - ux + 7);
        }
    }

    // ---- head loop: S -> softmax -> P -> PV -> OT/O2 ----
    for (int h = 0; h < 4; h++){
        // S: A = Q rows (K=16 zero-padded to 32: quads 2,3 zeroed)
        short8 aq = *(const short8*)&bufQ[(16*wq + col)*LS + h*16 + (qd & 1)*8];
        if (qd >= 2) aq = zero8;
        float4v acc_s[4];
        #pragma unroll
        for (int jn = 0; jn < 4; jn++){
            int u = 16*jn + col;
            short8 bk = *(const short8*)&bufK[u*LS + h*16 + (qd & 1)*8]; // finite; x0 for qd>=2
            acc_s[jn] = MFMA(aq, bk, zf);
        }
        // bias + softmax over u (4 jn regs x 16 lanes)
        float pr[4][4];
        #pragma unroll
        for (int jn = 0; jn < 4; jn++)
            #pragma unroll
            for (int r = 0; r < 4; r++)
                pr[jn][r] = acc_s[jn][r] + rpb_lds[idx_t[jn][r]*4 + h];
        #pragma unroll
        for (int r = 0; r < 4; r++){
            float m = fmaxf(fmaxf(pr[0][r], pr[1][r]), fmaxf(pr[2][r], pr[3][r]));
            m = fmaxf(m, __shfl_xor(m, 1)); m = fmaxf(m, __shfl_xor(m, 2));
            m = fmaxf(m, __shfl_xor(m, 4)); m = fmaxf(m, __shfl_xor(m, 8));
            float s = 0.f;
            #pragma unroll
            for (int jn = 0; jn < 4; jn++){ pr[jn][r] = __expf(pr[jn][r] - m); s += pr[jn][r]; }
            s += __shfl_xor(s, 1); s += __shfl_xor(s, 2);
            s += __shfl_xor(s, 4); s += __shfl_xor(s, 8);
            float rc = 1.f / s;
            #pragma unroll
            for (int jn = 0; jn < 4; jn++)
                bufP[(16*wq + 4*qd + r)*LS + 16*jn + col] = f2bs(pr[jn][r] * rc);
        }
        __syncthreads();
        // PV: o[t][d], K=64 over u
        short8 ap0 = *(const short8*)&bufP[(16*wq + col)*LS + 8*qd];
        short8 ap1 = *(const short8*)&bufP[(16*wq + col)*LS + 32 + 8*qd];
        short8 bv0 = *(const short8*)&bufV[(h*16 + col)*LS + 8*qd];
        short8 bv1 = *(const short8*)&bufV[(h*16 + col)*LS + 32 + 8*qd];
        float4v acc_o = zf;
        acc_o = MFMA(ap0, bv0, acc_o);
        acc_o = MFMA(ap1, bv1, acc_o);
        __syncthreads();          // all PV reads of V_h / P done
        // write OT (over dead V_h rows) and O2 (over dead K_h cols)
        short4v ot;
        #pragma unroll
        for (int r = 0; r < 4; r++) ot[r] = f2bs(acc_o[r]);
        *(short4v*)&bufV[(h*16 + col)*LS + 16*wq + 4*qd] = ot;
        #pragma unroll
        for (int r = 0; r < 4; r++)
            bufK[(16*wq + 4*qd + r)*LS + h*16 + col] = ot[r];
    }
    __syncthreads();

    // ---- energy = Y Y^T (16x16, K=256), shared-frag MFMA; all waves redundant ----
    {
        float4v acc_e = zf;
        #pragma unroll
        for (int h = 0; h < 4; h++){
            short8 f0 = *(const short8*)&bufV[(h*16 + col)*LS + 8*qd];
            short8 f1 = *(const short8*)&bufV[(h*16 + col)*LS + 32 + 8*qd];
            acc_e = MFMA(f0, f0, acc_e);
            acc_e = MFMA(f1, f1, acc_e);
        }
        if (wq == 0){
            #pragma unroll
            for (int r = 0; r < 4; r++) energyS[(4*qd + r)*16 + col] = acc_e[r];
        }
    }
    __syncthreads();
    // ---- softmax over energy rows -> soft_bf (bf16, upper 16 cols zero) ----
    if (tid < 16){
        int i = tid; float m = -1e30f;
        for (int j = 0; j < 16; j++) m = fmaxf(m, energyS[i*16 + j]);
        float s = 0.f; float e[16];
        for (int j = 0; j < 16; j++){ e[j] = __expf(energyS[i*16 + j] - m); s += e[j]; }
        float rc = 1.f / s;
        for (int j = 0; j < 16; j++) soft_bf[i*32 + j] = f2bs(e[j] * rc);
        for (int j = 0; j < 16; j++) soft_bf[i*32 + 16 + j] = 0;
    }
    __syncthreads();

    // ---- lam (per wave: head h=wq) + assemble XO -> bufP ----
    {
        int h = wq;
        float gam = gammap[0];
        short8 asf = *(const short8*)&soft_bf[col*32 + 8*qd];  // real zeros for k>=16
        #pragma unroll
        for (int jn = 0; jn < 4; jn++){
            int t = 16*jn + col;
            short8 bo = *(const short8*)&bufK[t*LS + h*16 + (qd & 1)*8]; // O2 rows; x0 for qd>=2
            float4v acc = MFMA(asf, bo, zf);
            short4v qv = *(const short4v*)&bufQ[t*LS + h*16 + 4*qd];
            short4v xv = *(const short4v*)&bufA[t*LS + h*16 + 4*qd];
            short4v pk;
            #pragma unroll
            for (int r = 0; r < 4; r++){
                float ot = bs2f(bufV[(h*16 + 4*qd + r)*LS + t]);
                float xo = gam*acc[r] + ot + bs2f(qv[r]) + bs2f(xv[r]);
                pk[r] = f2bs(xo);
            }
            *(short4v*)&bufP[t*LS + h*16 + 4*qd] = pk;
        }
    }
    __syncthreads();

    // ---- proj: XO · Wp^T + pb -> global (in place over x1) ----
    {
        short8 a0 = *(const short8*)&bufP[(16*wq + col)*LS + 8*qd];
        short8 a1 = *(const short8*)&bufP[(16*wq + col)*LS + 32 + 8*qd];
        #pragma unroll
        for (int jn = 0; jn < 4; jn++){
            int c = 16*jn + col;
            short8 b0 = load_w8(pw + (size_t)c*64 + 8*qd);
            short8 b1 = load_w8(pw + (size_t)c*64 + 32 + 8*qd);
            float4v acc = zf;
            acc = MFMA(a0, b0, acc);
            acc = MFMA(a1, b1, acc);
            float pbv = pb[c];
            float4v outv;
            #pragma unroll
            for (int r = 0; r < 4; r++) outv[r] = acc[r] + pbv;
            int t0 = 16*wq + 4*qd;
            *(float4v*)(x1 + base + (size_t)c*HW + HWOF(t0)) = outv;
        }
    }
    #undef HWOF
}

// ---------------- Kernel 5: channel-MLP with pre-LN, in place on xo ----------------
__global__ __launch_bounds__(256) void k_mlp(float* __restrict__ xo,
                                             const float* __restrict__ g, const float* __restrict__ bb,
                                             const float* __restrict__ w1, const float* __restrict__ b1,
                                             const float* __restrict__ w2, const float* __restrict__ b2){
    __shared__ float W1[64][64], W2[64][64];
    int tid = threadIdx.x;
    for (int e = tid; e < 4096; e += 256){ W1[e>>6][e&63] = w1[e]; W2[e>>6][e&63] = w2[e]; }
    __syncthreads();
    int gp = blockIdx.x * 256 + tid;           // 262144 positions
    int b = gp >> 14, hw = gp & 16383;
    size_t base = (size_t)b * NPLANE + hw;

    float t[64];
    float mean = 0.f;
    #pragma unroll
    for (int c = 0; c < 64; c++){ t[c] = xo[base + (size_t)c*HW]; mean += t[c]; }
    mean *= (1.f/64.f);
    float var = 0.f;
    #pragma unroll
    for (int c = 0; c < 64; c++){ float d = t[c] - mean; var += d*d; }
    var *= (1.f/64.f);
    float rstd = rsqrtf(var + EPS);
    float tn[64];
    #pragma unroll
    for (int c = 0; c < 64; c++) tn[c] = (t[c] - mean) * rstd * g[c] + bb[c];

    float h1[64];
    #pragma unroll
    for (int j = 0; j < 64; j++){
        float acc = b1[j];
        #pragma unroll
        for (int c = 0; c < 64; c++) acc += tn[c] * W1[j][c];
        h1[j] = gelu_exact(acc);
    }
    #pragma unroll
    for (int c2 = 0; c2 < 64; c2++){
        float acc = b2[c2];
        #pragma unroll
        for (int j = 0; j < 64; j++) acc += h1[j] * W2[c2][j];
        xo[base + (size_t)c2*HW] = t[c2] + acc;
    }
}

extern "C" void kernel_launch(void* const* d_in, const int* in_sizes, int n_in,
                              void* d_out, int out_size, void* d_ws, size_t ws_size,
                              hipStream_t stream){
    const float* x        = (const float*)d_in[0];
    const float* l1_g1    = (const float*)d_in[1];
    const float* l1_b1    = (const float*)d_in[2];
    const float* l1_cw    = (const float*)d_in[3];
    const float* l1_cb    = (const float*)d_in[4];
    const float* l1_g2    = (const float*)d_in[5];
    const float* l1_b2    = (const float*)d_in[6];
    const float* l2_g1    = (const float*)d_in[7];
    const float* l2_b1    = (const float*)d_in[8];
    const float* l2_cw    = (const float*)d_in[9];
    const float* l2_cb    = (const float*)d_in[10];
    const float* l2_g2    = (const float*)d_in[11];
    const float* l2_b2    = (const float*)d_in[12];
    const float* pos1     = (const float*)d_in[13];
    const float* pos2     = (const float*)d_in[14];
    const float* q_w      = (const float*)d_in[15];
    const float* q_b      = (const float*)d_in[16];
    const float* kv_w     = (const float*)d_in[17];
    const float* kv_b     = (const float*)d_in[18];
    const float* rpb      = (const float*)d_in[19];
    const float* gamma    = (const float*)d_in[20];
    const float* proj_w   = (const float*)d_in[21];
    const float* proj_b   = (const float*)d_in[22];
    const float* norm2_g  = (const float*)d_in[23];
    const float* norm2_b  = (const float*)d_in[24];
    const float* fc1_w    = (const float*)d_in[25];
    const float* fc1_b    = (const float*)d_in[26];
    const float* fc2_w    = (const float*)d_in[27];
    const float* fc2_b    = (const float*)d_in[28];

    float* out = (float*)d_out;                // y1 -> xo -> final, in place

    float* y2   = (float*)d_ws;                // 16.7M floats (67 MB)
    float* mu   = y2 + (size_t)16*NPLANE;
    float* rinv = mu + 1024;

    k_stats  <<<1024, 256, 0, stream>>>(x, mu, rinv);
    k_conv   <<<4096, 256, 0, stream>>>(x, mu, rinv,
                                        l1_g1, l1_b1, l1_cw, l1_cb,
                                        l2_g1, l2_b1, l2_cw, l2_cb, out, y2);
    k_ln2gelu<<<2048, 256, 0, stream>>>(out, y2, l1_g2, l1_b2, l2_g2, l2_b2);
    k_attn   <<<4096, 256, 0, stream>>>(out, y2, pos1, pos2, q_w, q_b, kv_w, kv_b,
                                        rpb, gamma, proj_w, proj_b);
    k_mlp    <<<1024, 256, 0, stream>>>(out, norm2_g, norm2_b, fc1_w, fc1_b, fc2_w, fc2_b);
}

// Round 4
// 576.975 us; speedup vs baseline: 2.6114x; 1.4728x over previous
//
#include <hip/hip_runtime.h>
#include <hip/hip_bf16.h>

typedef __hip_bfloat16 bf16;
typedef __attribute__((ext_vector_type(8))) short short8;
typedef __attribute__((ext_vector_type(4))) short short4v;
typedef __attribute__((ext_vector_type(4))) float float4v;

__device__ __forceinline__ float b2f(bf16 v){ return __bfloat162float(v); }
__device__ __forceinline__ bf16 f2b(float f){ return __float2bfloat16(f); }
__device__ __forceinline__ short f2bs(float f){
    union { bf16 h; short s; } u; u.h = __float2bfloat16(f); return u.s;
}
__device__ __forceinline__ float bs2f(short s){
    return __uint_as_float(((unsigned)(unsigned short)s) << 16);
}
__device__ __forceinline__ float gelu_exact(float x){
    return 0.5f * x * (1.0f + erff(x * 0.70710678118654752440f));
}
// load 8 consecutive floats -> bf16 frag
__device__ __forceinline__ short8 load_w8(const float* p){
    float4v w0 = *(const float4v*)p;
    float4v w1 = *(const float4v*)(p + 4);
    short8 r;
    r[0]=f2bs(w0[0]); r[1]=f2bs(w0[1]); r[2]=f2bs(w0[2]); r[3]=f2bs(w0[3]);
    r[4]=f2bs(w1[0]); r[5]=f2bs(w1[1]); r[6]=f2bs(w1[2]); r[7]=f2bs(w1[3]);
    return r;
}
#define MFMA(a,b,c) __builtin_amdgcn_mfma_f32_16x16x32_bf16((a),(b),(c),0,0,0)

#define HW 16384          // 128*128
#define NPLANE 1048576    // 64*16384 per batch
#define EPS 1e-5f
#define LS 72             // LDS row stride in bf16 (144 B, 16B-aligned rows)

// ---------------- Kernel 1: per-(b,c) LN stats over H*W ----------------
__global__ __launch_bounds__(256) void k_stats(const float* __restrict__ x,
                                               float* __restrict__ mu,
                                               float* __restrict__ rinv){
    int bc = blockIdx.x;                       // 0..1023
    const float* p = x + (size_t)bc * HW;
    float s = 0.f, ss = 0.f;
    for (int i = threadIdx.x; i < HW; i += 256){
        float v = p[i]; s += v; ss += v*v;
    }
    __shared__ float rs[256], rss[256];
    rs[threadIdx.x] = s; rss[threadIdx.x] = ss; __syncthreads();
    for (int st = 128; st > 0; st >>= 1){
        if (threadIdx.x < st){ rs[threadIdx.x] += rs[threadIdx.x+st]; rss[threadIdx.x] += rss[threadIdx.x+st]; }
        __syncthreads();
    }
    if (threadIdx.x == 0){
        float m = rs[0] * (1.f/HW);
        float v = rss[0] * (1.f/HW) - m*m;
        mu[bc] = m; rinv[bc] = rsqrtf(v + EPS);
    }
}

// ---------------- Kernel 2: LN1 + 1x1 conv, both branches (MFMA) ----------------
// y_br[b,o,hw] = g1[hw]*(W·xn)[o,hw] + b1[hw]*rowsum(W)[o] + cb[o]
__global__ __launch_bounds__(256) void k_conv(const float* __restrict__ x,
                                              const float* __restrict__ mu,
                                              const float* __restrict__ rinv,
                                              const float* __restrict__ g1a, const float* __restrict__ b1a,
                                              const float* __restrict__ w1,  const float* __restrict__ cb1,
                                              const float* __restrict__ g1b, const float* __restrict__ b1b,
                                              const float* __restrict__ w2,  const float* __restrict__ cb2,
                                              float* __restrict__ y1, float* __restrict__ y2){
    int blk = blockIdx.x;          // 16*256 blocks
    int b = blk >> 8; int tile = blk & 255; int hw0 = tile * 64;
    __shared__ __align__(16) short xn_bf[64*LS];   // [p][c] transposed, LN applied
    __shared__ float rowsumS[2][64];
    const int tid = threadIdx.x;
    const int wq = tid >> 6, lane = tid & 63, qd = lane >> 4, col = lane & 15;
    const float4v zf = {0.f,0.f,0.f,0.f};

    for (int i = tid; i < 1024; i += 256){
        int c = i >> 4, p0 = (i & 15) * 4;
        int bc = b*64 + c;
        float m = mu[bc], rv = rinv[bc];
        float4v v = *(const float4v*)(x + (size_t)bc*HW + hw0 + p0);
        #pragma unroll
        for (int k = 0; k < 4; k++) xn_bf[(p0+k)*LS + c] = f2bs((v[k] - m) * rv);
    }
    if (tid < 128){
        int br = tid >> 6, o = tid & 63;
        const float* W = br ? w2 : w1;
        float s = 0.f;
        for (int c = 0; c < 64; c++) s += W[o*64 + c];
        rowsumS[br][o] = s;
    }
    __syncthreads();

    #pragma unroll
    for (int br = 0; br < 2; br++){
        const float* W  = br ? w2  : w1;
        const float* cb = br ? cb2 : cb1;
        const float* gp = br ? g1b : g1a;
        const float* bp = br ? b1b : b1a;
        float* y = br ? y2 : y1;
        short8 a0 = load_w8(W + (size_t)(16*wq + col)*64 + 8*qd);
        short8 a1 = load_w8(W + (size_t)(16*wq + col)*64 + 32 + 8*qd);
        float cbv[4], rsv[4];
        #pragma unroll
        for (int r = 0; r < 4; r++){
            int o = 16*wq + 4*qd + r;
            cbv[r] = cb[o]; rsv[r] = rowsumS[br][o];
        }
        #pragma unroll
        for (int jn = 0; jn < 4; jn++){
            short8 bx0 = *(const short8*)&xn_bf[(16*jn + col)*LS + 8*qd];
            short8 bx1 = *(const short8*)&xn_bf[(16*jn + col)*LS + 32 + 8*qd];
            float4v acc = zf;
            acc = MFMA(a0, bx0, acc);
            acc = MFMA(a1, bx1, acc);
            int hw = hw0 + 16*jn + col;
            float gl = gp[hw], bl = bp[hw];
            #pragma unroll
            for (int r = 0; r < 4; r++){
                int o = 16*wq + 4*qd + r;
                y[(size_t)(b*64 + o)*HW + hw] = gl*acc[r] + bl*rsv[r] + cbv[r];
            }
        }
    }
}

// ---------------- Kernel 3: LN2 over (H,W) + exact GELU, in place ----------------
__global__ __launch_bounds__(256) void k_ln2gelu(float* __restrict__ y1, float* __restrict__ y2,
                                                 const float* __restrict__ g2a, const float* __restrict__ b2a,
                                                 const float* __restrict__ g2b, const float* __restrict__ b2b){
    int blk = blockIdx.x;                      // 2048: br*1024 + bc
    int br = blk >> 10; int bc = blk & 1023;
    float* y = br ? y2 : y1;
    const float* g  = br ? g2b : g2a;
    const float* bb = br ? b2b : b2a;
    float* p = y + (size_t)bc * HW;
    float s = 0.f, ss = 0.f;
    for (int i = threadIdx.x; i < HW; i += 256){
        float v = p[i]; s += v; ss += v*v;
    }
    __shared__ float rs[256], rss[256];
    __shared__ float smu, srinv;
    rs[threadIdx.x] = s; rss[threadIdx.x] = ss; __syncthreads();
    for (int st = 128; st > 0; st >>= 1){
        if (threadIdx.x < st){ rs[threadIdx.x] += rs[threadIdx.x+st]; rss[threadIdx.x] += rss[threadIdx.x+st]; }
        __syncthreads();
    }
    if (threadIdx.x == 0){
        float m = rs[0] * (1.f/HW);
        float v = rss[0] * (1.f/HW) - m*m;
        smu = m; srinv = rsqrtf(v + EPS);
    }
    __syncthreads();
    for (int i = threadIdx.x; i < HW; i += 256){
        float v = (p[i] - smu) * srinv * g[i] + bb[i];
        p[i] = gelu_exact(v);
    }
}

// ---------------- Kernel 4: per-window attention + LAM + proj (MFMA) ----------------
// x1 lives in d_out; xo written in place over x1 (same per-block address set).
__global__ __launch_bounds__(256) void k_attn(float* __restrict__ x1, const float* __restrict__ x2,
                                              const float* __restrict__ pos1, const float* __restrict__ pos2,
                                              const float* __restrict__ qw, const float* __restrict__ qb,
                                              const float* __restrict__ kvw, const float* __restrict__ kvb,
                                              const float* __restrict__ rpb, const float* __restrict__ gammap,
                                              const float* __restrict__ pw, const float* __restrict__ pb){
    int wid = blockIdx.x;                      // 4096 windows
    int b = wid >> 8; int r0 = wid & 255; int hy = r0 >> 4; int wx = r0 & 15;

    __shared__ __align__(16) short bufA[64*LS];   // X2 -> X1 (bf16, +pos)
    __shared__ __align__(16) short bufK[64*LS];   // K[t][c] -> O2[t][c]
    __shared__ __align__(16) short bufV[64*LS];   // VT[c][t] -> OT[c][t]
    __shared__ __align__(16) short bufQ[64*LS];   // Q[t][c] (scaled)
    __shared__ __align__(16) short bufP[64*LS];   // P[t][u] per head -> XO[t][c]
    __shared__ float rpb_lds[900];
    __shared__ float energyS[256];
    __shared__ __align__(16) short soft_bf[16*32]; // soft rows, upper 16 cols = 0

    const int tid = threadIdx.x;
    const int wq = tid >> 6, lane = tid & 63, qd = lane >> 4, col = lane & 15;
    size_t base = (size_t)b * NPLANE;
    #define HWOF(t) ((hy*8 + ((t)>>3))*128 + wx*8 + ((t)&7))

    const float4v zf = {0.f,0.f,0.f,0.f};
    const short8 zero8 = {0,0,0,0,0,0,0,0};

    for (int i = tid; i < 900; i += 256) rpb_lds[i] = rpb[i];

    // ---- load X2 (+pos2) -> bufA ----
    for (int i = tid; i < 1024; i += 256){
        int c = i >> 4, t0 = (i & 15) * 4;
        float4v v = *(const float4v*)(x2 + base + (size_t)c*HW + HWOF(t0));
        #pragma unroll
        for (int k = 0; k < 4; k++)
            bufA[(t0+k)*LS + c] = f2bs(v[k] + pos2[(t0+k)*64 + c]);
    }
    __syncthreads();

    // ---- VT = Wv · X2^T ----
    {
        float bvr[4];
        #pragma unroll
        for (int r = 0; r < 4; r++) bvr[r] = kvb[64 + 16*wq + 4*qd + r];
        short8 a0 = load_w8(kvw + (size_t)(64 + 16*wq + col)*64 + 8*qd);
        short8 a1 = load_w8(kvw + (size_t)(64 + 16*wq + col)*64 + 32 + 8*qd);
        #pragma unroll
        for (int jn = 0; jn < 4; jn++){
            int u = 16*jn + col;
            short8 b0 = *(const short8*)&bufA[u*LS + 8*qd];
            short8 b1 = *(const short8*)&bufA[u*LS + 32 + 8*qd];
            float4v acc = zf;
            acc = MFMA(a0, b0, acc);
            acc = MFMA(a1, b1, acc);
            #pragma unroll
            for (int r = 0; r < 4; r++)
                bufV[(16*wq + 4*qd + r)*LS + u] = f2bs(acc[r] + bvr[r]);
        }
    }
    // ---- K = X2 · Wk^T ----
    {
        short8 ax0 = *(const short8*)&bufA[(16*wq + col)*LS + 8*qd];
        short8 ax1 = *(const short8*)&bufA[(16*wq + col)*LS + 32 + 8*qd];
        #pragma unroll
        for (int jn = 0; jn < 4; jn++){
            int co = 16*jn + col;
            short8 b0 = load_w8(kvw + (size_t)co*64 + 8*qd);
            short8 b1 = load_w8(kvw + (size_t)co*64 + 32 + 8*qd);
            float4v acc = zf;
            acc = MFMA(ax0, b0, acc);
            acc = MFMA(ax1, b1, acc);
            float kb = kvb[co];
            #pragma unroll
            for (int r = 0; r < 4; r++)
                bufK[(16*wq + 4*qd + r)*LS + co] = f2bs(acc[r] + kb);
        }
    }
    __syncthreads();

    // ---- load X1 (+pos1) -> bufA ----
    for (int i = tid; i < 1024; i += 256){
        int c = i >> 4, t0 = (i & 15) * 4;
        float4v v = *(const float4v*)(x1 + base + (size_t)c*HW + HWOF(t0));
        #pragma unroll
        for (int k = 0; k < 4; k++)
            bufA[(t0+k)*LS + c] = f2bs(v[k] + pos1[(t0+k)*64 + c]);
    }
    __syncthreads();

    // ---- Q = 0.25 * (X1 · Wq^T + qb) ----
    {
        short8 ax0 = *(const short8*)&bufA[(16*wq + col)*LS + 8*qd];
        short8 ax1 = *(const short8*)&bufA[(16*wq + col)*LS + 32 + 8*qd];
        #pragma unroll
        for (int jn = 0; jn < 4; jn++){
            int co = 16*jn + col;
            short8 b0 = load_w8(qw + (size_t)co*64 + 8*qd);
            short8 b1 = load_w8(qw + (size_t)co*64 + 32 + 8*qd);
            float4v acc = zf;
            acc = MFMA(ax0, b0, acc);
            acc = MFMA(ax1, b1, acc);
            float qbv = qb[co];
            #pragma unroll
            for (int r = 0; r < 4; r++)
                bufQ[(16*wq + 4*qd + r)*LS + co] = f2bs((acc[r] + qbv) * 0.25f);
        }
    }
    __syncthreads();

    int idx_t[4][4];
    #pragma unroll
    for (int jn = 0; jn < 4; jn++){
        int u = 16*jn + col; int uy = u >> 3, ux = u & 7;
        #pragma unroll
        for (int r = 0; r < 4; r++){
            int t = 16*wq + 4*qd + r;
            idx_t[jn][r] = ((t>>3) - uy + 7)*15 + ((t&7) - ux + 7);
        }
    }

    // ---- head loop: S -> softmax -> P -> PV -> OT/O2 ----
    for (int h = 0; h < 4; h++){
        short8 aq = *(const short8*)&bufQ[(16*wq + col)*LS + h*16 + (qd & 1)*8];
        if (qd >= 2) aq = zero8;
        float4v acc_s[4];
        #pragma unroll
        for (int jn = 0; jn < 4; jn++){
            int u = 16*jn + col;
            short8 bk = *(const short8*)&bufK[u*LS + h*16 + (qd & 1)*8];
            acc_s[jn] = MFMA(aq, bk, zf);
        }
        float pr[4][4];
        #pragma unroll
        for (int jn = 0; jn < 4; jn++)
            #pragma unroll
            for (int r = 0; r < 4; r++)
                pr[jn][r] = acc_s[jn][r] + rpb_lds[idx_t[jn][r]*4 + h];
        #pragma unroll
        for (int r = 0; r < 4; r++){
            float m = fmaxf(fmaxf(pr[0][r], pr[1][r]), fmaxf(pr[2][r], pr[3][r]));
            m = fmaxf(m, __shfl_xor(m, 1)); m = fmaxf(m, __shfl_xor(m, 2));
            m = fmaxf(m, __shfl_xor(m, 4)); m = fmaxf(m, __shfl_xor(m, 8));
            float s = 0.f;
            #pragma unroll
            for (int jn = 0; jn < 4; jn++){ pr[jn][r] = __expf(pr[jn][r] - m); s += pr[jn][r]; }
            s += __shfl_xor(s, 1); s += __shfl_xor(s, 2);
            s += __shfl_xor(s, 4); s += __shfl_xor(s, 8);
            float rc = 1.f / s;
            #pragma unroll
            for (int jn = 0; jn < 4; jn++)
                bufP[(16*wq + 4*qd + r)*LS + 16*jn + col] = f2bs(pr[jn][r] * rc);
        }
        __syncthreads();
        short8 ap0 = *(const short8*)&bufP[(16*wq + col)*LS + 8*qd];
        short8 ap1 = *(const short8*)&bufP[(16*wq + col)*LS + 32 + 8*qd];
        short8 bv0 = *(const short8*)&bufV[(h*16 + col)*LS + 8*qd];
        short8 bv1 = *(const short8*)&bufV[(h*16 + col)*LS + 32 + 8*qd];
        float4v acc_o = zf;
        acc_o = MFMA(ap0, bv0, acc_o);
        acc_o = MFMA(ap1, bv1, acc_o);
        __syncthreads();
        short4v ot;
        #pragma unroll
        for (int r = 0; r < 4; r++) ot[r] = f2bs(acc_o[r]);
        *(short4v*)&bufV[(h*16 + col)*LS + 16*wq + 4*qd] = ot;
        #pragma unroll
        for (int r = 0; r < 4; r++)
            bufK[(16*wq + 4*qd + r)*LS + h*16 + col] = ot[r];
    }
    __syncthreads();

    // ---- energy = Y Y^T (16x16, K=256) ----
    {
        float4v acc_e = zf;
        #pragma unroll
        for (int h = 0; h < 4; h++){
            short8 f0 = *(const short8*)&bufV[(h*16 + col)*LS + 8*qd];
            short8 f1 = *(const short8*)&bufV[(h*16 + col)*LS + 32 + 8*qd];
            acc_e = MFMA(f0, f0, acc_e);
            acc_e = MFMA(f1, f1, acc_e);
        }
        if (wq == 0){
            #pragma unroll
            for (int r = 0; r < 4; r++) energyS[(4*qd + r)*16 + col] = acc_e[r];
        }
    }
    __syncthreads();
    if (tid < 16){
        int i = tid; float m = -1e30f;
        for (int j = 0; j < 16; j++) m = fmaxf(m, energyS[i*16 + j]);
        float s = 0.f; float e[16];
        for (int j = 0; j < 16; j++){ e[j] = __expf(energyS[i*16 + j] - m); s += e[j]; }
        float rc = 1.f / s;
        for (int j = 0; j < 16; j++) soft_bf[i*32 + j] = f2bs(e[j] * rc);
        for (int j = 0; j < 16; j++) soft_bf[i*32 + 16 + j] = 0;
    }
    __syncthreads();

    // ---- lam (per wave: head h=wq) + assemble XO -> bufP ----
    {
        int h = wq;
        float gam = gammap[0];
        short8 asf = *(const short8*)&soft_bf[col*32 + 8*qd];
        #pragma unroll
        for (int jn = 0; jn < 4; jn++){
            int t = 16*jn + col;
            short8 bo = *(const short8*)&bufK[t*LS + h*16 + (qd & 1)*8];
            float4v acc = MFMA(asf, bo, zf);
            short4v qv = *(const short4v*)&bufQ[t*LS + h*16 + 4*qd];
            short4v xv = *(const short4v*)&bufA[t*LS + h*16 + 4*qd];
            short4v pk;
            #pragma unroll
            for (int r = 0; r < 4; r++){
                float ot = bs2f(bufV[(h*16 + 4*qd + r)*LS + t]);
                float xo = gam*acc[r] + ot + bs2f(qv[r]) + bs2f(xv[r]);
                pk[r] = f2bs(xo);
            }
            *(short4v*)&bufP[t*LS + h*16 + 4*qd] = pk;
        }
    }
    __syncthreads();

    // ---- proj: XO · Wp^T + pb -> global (in place over x1) ----
    {
        short8 a0 = *(const short8*)&bufP[(16*wq + col)*LS + 8*qd];
        short8 a1 = *(const short8*)&bufP[(16*wq + col)*LS + 32 + 8*qd];
        #pragma unroll
        for (int jn = 0; jn < 4; jn++){
            int c = 16*jn + col;
            short8 b0 = load_w8(pw + (size_t)c*64 + 8*qd);
            short8 b1 = load_w8(pw + (size_t)c*64 + 32 + 8*qd);
            float4v acc = zf;
            acc = MFMA(a0, b0, acc);
            acc = MFMA(a1, b1, acc);
            float pbv = pb[c];
            float4v outv;
            #pragma unroll
            for (int r = 0; r < 4; r++) outv[r] = acc[r] + pbv;
            int t0 = 16*wq + 4*qd;
            *(float4v*)(x1 + base + (size_t)c*HW + HWOF(t0)) = outv;
        }
    }
    #undef HWOF
}

// ---------------- Kernel 5: channel-MLP with pre-LN, in place on xo (MFMA) ----------------
__global__ __launch_bounds__(256) void k_mlp(float* __restrict__ xo,
                                             const float* __restrict__ g, const float* __restrict__ bb,
                                             const float* __restrict__ w1, const float* __restrict__ fb1,
                                             const float* __restrict__ w2, const float* __restrict__ fb2){
    int blk = blockIdx.x;                      // 4096: b*256 + tile
    int b = blk >> 8; int tile = blk & 255; int hw0 = tile * 64;
    __shared__ float Xf[64][65];               // [p][c] fp32 (residual + stats)
    __shared__ __align__(16) short tn_bf[64*LS];
    __shared__ __align__(16) short h1_bf[64*LS];
    __shared__ float sumS[4][64], sqS[4][64];
    __shared__ float muS[64], rinvS[64];
    const int tid = threadIdx.x;
    const int wq = tid >> 6, lane = tid & 63, qd = lane >> 4, col = lane & 15;
    const float4v zf = {0.f,0.f,0.f,0.f};
    size_t base = (size_t)b * NPLANE + hw0;

    for (int i = tid; i < 1024; i += 256){
        int c = i >> 4, p0 = (i & 15) * 4;
        float4v v = *(const float4v*)(xo + base + (size_t)c*HW + p0);
        #pragma unroll
        for (int k = 0; k < 4; k++) Xf[p0+k][c] = v[k];
    }
    __syncthreads();
    {
        int p = tid & 63, qg = tid >> 6;
        float s = 0.f, ss = 0.f;
        #pragma unroll
        for (int j = 0; j < 16; j++){ float v = Xf[p][qg*16 + j]; s += v; ss += v*v; }
        sumS[qg][p] = s; sqS[qg][p] = ss;
    }
    __syncthreads();
    if (tid < 64){
        float s  = sumS[0][tid] + sumS[1][tid] + sumS[2][tid] + sumS[3][tid];
        float ss = sqS[0][tid]  + sqS[1][tid]  + sqS[2][tid]  + sqS[3][tid];
        float m = s * (1.f/64.f);
        float var = ss * (1.f/64.f) - m*m;
        muS[tid] = m; rinvS[tid] = rsqrtf(var + EPS);
    }
    __syncthreads();
    {
        int p = tid & 63, qg = tid >> 6;
        float m = muS[p], rv = rinvS[p];
        #pragma unroll
        for (int j = 0; j < 16; j++){
            int c = qg*16 + j;
            tn_bf[p*LS + c] = f2bs((Xf[p][c] - m) * rv * g[c] + bb[c]);
        }
    }
    __syncthreads();
    // GEMM1: h1 = gelu(tn @ W1^T + fb1)
    {
        short8 a0 = *(const short8*)&tn_bf[(16*wq + col)*LS + 8*qd];
        short8 a1 = *(const short8*)&tn_bf[(16*wq + col)*LS + 32 + 8*qd];
        #pragma unroll
        for (int jn = 0; jn < 4; jn++){
            int j = 16*jn + col;
            short8 f0 = load_w8(w1 + (size_t)j*64 + 8*qd);
            short8 f1 = load_w8(w1 + (size_t)j*64 + 32 + 8*qd);
            float4v acc = zf;
            acc = MFMA(a0, f0, acc);
            acc = MFMA(a1, f1, acc);
            float bv = fb1[j];
            #pragma unroll
            for (int r = 0; r < 4; r++)
                h1_bf[(16*wq + 4*qd + r)*LS + j] = f2bs(gelu_exact(acc[r] + bv));
        }
    }
    __syncthreads();
    // GEMM2: out = t + h1 @ W2^T + fb2
    {
        short8 a0 = *(const short8*)&h1_bf[(16*wq + col)*LS + 8*qd];
        short8 a1 = *(const short8*)&h1_bf[(16*wq + col)*LS + 32 + 8*qd];
        #pragma unroll
        for (int jn = 0; jn < 4; jn++){
            int c2 = 16*jn + col;
            short8 f0 = load_w8(w2 + (size_t)c2*64 + 8*qd);
            short8 f1 = load_w8(w2 + (size_t)c2*64 + 32 + 8*qd);
            float4v acc = zf;
            acc = MFMA(a0, f0, acc);
            acc = MFMA(a1, f1, acc);
            float bv = fb2[c2];
            float4v ov;
            #pragma unroll
            for (int r = 0; r < 4; r++)
                ov[r] = acc[r] + bv + Xf[16*wq + 4*qd + r][c2];
            *(float4v*)(xo + base + (size_t)c2*HW + 16*wq + 4*qd) = ov;
        }
    }
}

extern "C" void kernel_launch(void* const* d_in, const int* in_sizes, int n_in,
                              void* d_out, int out_size, void* d_ws, size_t ws_size,
                              hipStream_t stream){
    const float* x        = (const float*)d_in[0];
    const float* l1_g1    = (const float*)d_in[1];
    const float* l1_b1    = (const float*)d_in[2];
    const float* l1_cw    = (const float*)d_in[3];
    const float* l1_cb    = (const float*)d_in[4];
    const float* l1_g2    = (const float*)d_in[5];
    const float* l1_b2    = (const float*)d_in[6];
    const float* l2_g1    = (const float*)d_in[7];
    const float* l2_b1    = (const float*)d_in[8];
    const float* l2_cw    = (const float*)d_in[9];
    const float* l2_cb    = (const float*)d_in[10];
    const float* l2_g2    = (const float*)d_in[11];
    const float* l2_b2    = (const float*)d_in[12];
    const float* pos1     = (const float*)d_in[13];
    const float* pos2     = (const float*)d_in[14];
    const float* q_w      = (const float*)d_in[15];
    const float* q_b      = (const float*)d_in[16];
    const float* kv_w     = (const float*)d_in[17];
    const float* kv_b     = (const float*)d_in[18];
    const float* rpb      = (const float*)d_in[19];
    const float* gamma    = (const float*)d_in[20];
    const float* proj_w   = (const float*)d_in[21];
    const float* proj_b   = (const float*)d_in[22];
    const float* norm2_g  = (const float*)d_in[23];
    const float* norm2_b  = (const float*)d_in[24];
    const float* fc1_w    = (const float*)d_in[25];
    const float* fc1_b    = (const float*)d_in[26];
    const float* fc2_w    = (const float*)d_in[27];
    const float* fc2_b    = (const float*)d_in[28];

    float* out = (float*)d_out;                // y1 -> xo -> final, in place

    float* y2   = (float*)d_ws;                // 16.7M floats (67 MB)
    float* mu   = y2 + (size_t)16*NPLANE;
    float* rinv = mu + 1024;

    k_stats  <<<1024, 256, 0, stream>>>(x, mu, rinv);
    k_conv   <<<4096, 256, 0, stream>>>(x, mu, rinv,
                                        l1_g1, l1_b1, l1_cw, l1_cb,
                                        l2_g1, l2_b1, l2_cw, l2_cb, out, y2);
    k_ln2gelu<<<2048, 256, 0, stream>>>(out, y2, l1_g2, l1_b2, l2_g2, l2_b2);
    k_attn   <<<4096, 256, 0, stream>>>(out, y2, pos1, pos2, q_w, q_b, kv_w, kv_b,
                                        rpb, gamma, proj_w, proj_b);
    k_mlp    <<<4096, 256, 0, stream>>>(out, norm2_g, norm2_b, fc1_w, fc1_b, fc2_w, fc2_b);
}